// Round 7
// baseline (529.277 us; speedup 1.0000x reference)
//
#include <hip/hip_runtime.h>
#include <hip/hip_bf16.h>

// DynaGraphNet round 7: register-tiled attention (lane owns 4 q-rows x 16-dim
// chunk). attn1: 16-lane group == head -> lane-local head scores, no shuffles.
// attn2: 2 shfl_xor per q per m to combine 4 dim-chunks. LDS return traffic
// cut 2-4x vs round 6 (the round-6 bottleneck: broadcast b128 reads replicate
// 16B to all 64 lanes). Rest of pipeline (enc/qkv/adj/diag/merges) unchanged.

#define NB 4
#define TT 48
#define NNODES 2000
#define HORZ 24
#define PART_Q 8000

#define D4(a,b) ((a).x*(b).x + (a).y*(b).y + (a).z*(b).z + (a).w*(b).w)
#define FMA4(o,p,v) { (o).x = fmaf((p),(v).x,(o).x); (o).y = fmaf((p),(v).y,(o).y); \
                      (o).z = fmaf((p),(v).z,(o).z); (o).w = fmaf((p),(v).w,(o).w); }

__device__ __forceinline__ float wsum64(float v) {
#pragma unroll
    for (int m = 1; m < 64; m <<= 1) v += __shfl_xor(v, m, 64);
    return v;
}

// ---- proj_w [64][768] -> pT4 [jb=192][h=64][4] ----
__global__ __launch_bounds__(256) void k_tr(const float* __restrict__ pw,
                                            float* __restrict__ pT) {
    int i = blockIdx.x * 256 + threadIdx.x;
    int h = i / 768, j = i - h * 768;
    pT[((j >> 2) * 64 + h) * 4 + (j & 3)] = pw[i];
}

// ---- encoder: conv+BN+ReLU+proj+LN+ReLU -> node[g][64] ----
__global__ __launch_bounds__(64) void k_enc(const float* __restrict__ x,
        const float* __restrict__ cw, const float* __restrict__ cb,
        const float* __restrict__ bg, const float* __restrict__ bb,
        const float* __restrict__ pT, const float* __restrict__ pb,
        const float* __restrict__ g1, const float* __restrict__ b1,
        float* __restrict__ node) {
    __shared__ float xs[8][52];
    __shared__ float hs[8][768];
    __shared__ float wc[16][4];
    int tid = threadIdx.x;
    int g0 = blockIdx.x * 8;

    if (tid < 16) {
        float s = bg[tid] * rsqrtf(1.0f + 1e-5f);
        wc[tid][0] = cw[tid * 3 + 0] * s;
        wc[tid][1] = cw[tid * 3 + 1] * s;
        wc[tid][2] = cw[tid * 3 + 2] * s;
        wc[tid][3] = cb[tid] * s + bb[tid];
    }
    for (int i = tid; i < 8 * TT; i += 64) {
        int m = i & 7, t = i >> 3;
        int g = g0 + m;
        int b = g / NNODES, n = g - b * NNODES;
        xs[m][t + 1] = x[(b * TT + t) * NNODES + n];
    }
    if (tid < 8) { xs[tid][0] = 0.f; xs[tid][TT + 1] = 0.f; }
    __syncthreads();

    for (int m = 0; m < 8; m++) {
        for (int j = tid; j < 16 * TT; j += 64) {
            int f = j / TT, t = j - f * TT;
            float h = wc[f][0] * xs[m][t] + wc[f][1] * xs[m][t + 1] +
                      wc[f][2] * xs[m][t + 2] + wc[f][3];
            hs[m][j] = fmaxf(h, 0.f);
        }
    }
    __syncthreads();

    float acc[8];
    float pbv = pb[tid];
#pragma unroll
    for (int m = 0; m < 8; m++) acc[m] = pbv;
    const float4* pT4v = (const float4*)pT;
    for (int jb = 0; jb < 192; ++jb) {
        float4 wv = pT4v[jb * 64 + tid];
#pragma unroll
        for (int m = 0; m < 8; m++) {
            float4 hv = *(const float4*)&hs[m][jb * 4];
            acc[m] += D4(wv, hv);
        }
    }
    float gg = g1[tid], bbv = b1[tid];
    for (int m = 0; m < 8; m++) {
        float v = acc[m];
        float sm = wsum64(v);
        float sq = wsum64(v * v);
        float mu = sm * (1.f / 64.f);
        float var = sq * (1.f / 64.f) - mu * mu;
        float z = (v - mu) * rsqrtf(var + 1e-5f) * gg + bbv;
        node[(g0 + m) * 64 + tid] = fmaxf(z, 0.f);
    }
}

// ---- qkv + src/dst projections, 8-node tile per block ----
__global__ __launch_bounds__(256) void k_qkv(const float* __restrict__ node,
        const float* __restrict__ ipw, const float* __restrict__ ipb,
        const float* __restrict__ sw, const float* __restrict__ sb,
        const float* __restrict__ dw, const float* __restrict__ db,
        float* __restrict__ Qb, float* __restrict__ Kb, float* __restrict__ Vb,
        float* __restrict__ Sb, float* __restrict__ Db) {
    __shared__ float nds[8][64];
    int tid = threadIdx.x;
    int g0 = blockIdx.x * 8;
    for (int i = tid; i < 8 * 64; i += 256) {
        nds[i >> 6][i & 63] = node[(size_t)g0 * 64 + i];
    }
    __syncthreads();

    int o = tid;
    const float* wrow; float bias;
    if (o < 192)      { wrow = ipw + o * 64;          bias = ipb[o]; }
    else if (o < 224) { wrow = sw + (o - 192) * 64;   bias = sb[o - 192]; }
    else              { wrow = dw + (o - 224) * 64;   bias = db[o - 224]; }

    float acc[8];
#pragma unroll
    for (int n = 0; n < 8; ++n) acc[n] = bias;

#pragma unroll
    for (int c = 0; c < 4; ++c) {
        const float4* wp = (const float4*)(wrow + c * 16);
        float4 w0 = wp[0], w1 = wp[1], w2 = wp[2], w3 = wp[3];
#pragma unroll
        for (int n = 0; n < 8; ++n) {
            const float4* nr = (const float4*)&nds[n][c * 16];
            float4 a0 = nr[0], a1 = nr[1], a2 = nr[2], a3 = nr[3];
            acc[n] += D4(a0, w0) + D4(a1, w1) + D4(a2, w2) + D4(a3, w3);
        }
    }

    if (o < 64) {
#pragma unroll
        for (int n = 0; n < 8; ++n) Qb[(size_t)(g0 + n) * 64 + o] = acc[n] * 0.25f;
    } else if (o < 128) {
        int oo = o - 64;
#pragma unroll
        for (int n = 0; n < 8; ++n) Kb[(size_t)(g0 + n) * 64 + oo] = acc[n];
    } else if (o < 192) {
        int oo = o - 128;
#pragma unroll
        for (int n = 0; n < 8; ++n) Vb[(size_t)(g0 + n) * 64 + oo] = acc[n];
    } else if (o < 224) {
        int oo = o - 192;
#pragma unroll
        for (int n = 0; n < 8; ++n) {
            float a = acc[n];
            Sb[(size_t)(g0 + n) * 32 + oo] = (a >= 0.f ? a : 0.2f * a);
        }
    } else {
        int oo = o - 224;
#pragma unroll
        for (int n = 0; n < 8; ++n) {
            float a = acc[n];
            Db[(size_t)(g0 + n) * 32 + oo] = (a >= 0.f ? a : 0.2f * a);
        }
    }
}

// ---- adjacency mask bits: grid 512 = b4 x qt32 x mc4; wave lane = m ----
__global__ __launch_bounds__(256) void k_adj(const float* __restrict__ Sbuf,
        const float* __restrict__ Dbuf, const float* __restrict__ es_p,
        unsigned* __restrict__ maskU, float* __restrict__ ssqP,
        float* __restrict__ adv) {
    __shared__ float Sl[64][32];
    __shared__ float ssqW[4][64];
    int tid = threadIdx.x, bid = blockIdx.x;
    int b = bid >> 7, qt = (bid >> 2) & 31, mc = bid & 3;
    int w = tid >> 6, l = tid & 63;
    int bbase = b * NNODES;
    int qg0 = bbase + qt * 64;
    float es = es_p[0];

    for (int k = 0; k < 2; ++k) {
        int idx = tid + k * 256;
        int row = idx >> 3, cc = idx & 7;
        int qv = qt * 64 + row;
        *(float4*)&Sl[row][cc * 4] =
            *(const float4*)(Sbuf + (size_t)(bbase + min(qv, NNODES - 1)) * 32 + cc * 4);
    }
    __syncthreads();

    float ssqAcc = 0.f;
#pragma unroll
    for (int tt = 0; tt < 2; ++tt) {
        int t = w + tt * 4;
        int mtb = mc * 512 + t * 64;
        int mb = mtb + l;
        bool mok = mb < NNODES;
        float4 dr[8];
        const float4* dp = (const float4*)(Dbuf + (size_t)(bbase + (mok ? mb : NNODES - 1)) * 32);
#pragma unroll
        for (int j = 0; j < 8; ++j) dr[j] = dp[j];

        unsigned lo = 0, hi = 0;
        for (int qq = 0; qq < 64; ++qq) {
            int qv = qt * 64 + qq;
            const float4* sp = (const float4*)&Sl[qq][0];
            float a = 0.f;
#pragma unroll
            for (int j = 0; j < 8; ++j) a += D4(sp[j], dr[j]);
            a *= es;
            if (!mok) a = 0.f;
            bool diag = (mb == qv);
            if (diag && qv < NNODES) adv[qg0 + qq] = a;
            bool bit = (a > 0.f) && !diag;
            float ssqq = wsum64(a * a);
            unsigned long long bal = __ballot(bit);
            if (qq == l) { lo = (unsigned)bal; hi = (unsigned)(bal >> 32); ssqAcc += ssqq; }
        }
        int qv = qt * 64 + l;
        if (qv < NNODES) {
            int widx = mc * 16 + t * 2;
            maskU[(size_t)widx * PART_Q + qg0 + l] = lo;
            maskU[(size_t)(widx + 1) * PART_Q + qg0 + l] = hi;
        }
    }
    ssqW[w][l] = ssqAcc;
    __syncthreads();
    if (tid < 64) {
        int qv = qt * 64 + tid;
        if (qv < NNODES)
            ssqP[(size_t)mc * PART_Q + qg0 + tid] =
                ssqW[0][tid] + ssqW[1][tid] + ssqW[2][tid] + ssqW[3][tid];
    }
}

// ---- diag fixup: set mask bit m==q iff ad > -norm ----
__global__ __launch_bounds__(256) void k_diag(const float* __restrict__ ssqP,
        const float* __restrict__ adv, unsigned* __restrict__ maskU) {
    int qg = blockIdx.x * 256 + threadIdx.x;
    if (qg >= PART_Q) return;
    float ss = ssqP[qg] + ssqP[PART_Q + qg] + ssqP[2 * PART_Q + qg] + ssqP[3 * PART_Q + qg];
    float norm = fmaxf(sqrtf(ss), 1e-12f);
    float ad = adv[qg];
    if (ad > -norm) {
        int qloc = qg % NNODES;
        size_t idx = (size_t)(qloc >> 5) * PART_Q + qg;
        maskU[idx] |= (1u << (qloc & 31));
    }
}

// ---- attn1: grid 512 = b4 x qb8 x mc16; block 4 waves x 64 q ----
// lane = (h, qs): head h, q-slot qs; owns q = qb*256 + w*64 + qs + 16*qi
// (qi=0..3). Head scores are lane-local (head h == dim chunk h*16..h*16+15).
__global__ __launch_bounds__(256, 2) void k_a1(const float* __restrict__ Qb,
        const float* __restrict__ Kb, const float* __restrict__ Vb,
        float* __restrict__ Part) {
    __shared__ float Kl[125][64];
    __shared__ float Vl[125][64];
    int tid = threadIdx.x, bid = blockIdx.x;
    int b = bid >> 7, qb = (bid >> 4) & 7, mc = bid & 15;
    int bbase = b * NNODES;
    int w = tid >> 6, l = tid & 63;
    int h = l >> 4, qs = l & 15;
    int qloc0 = qb * 256 + w * 64 + qs;

    for (int k = 0; k < 16; ++k) {
        int idx = tid + k * 256;
        if (idx < 4000) {
            int arr = idx >= 2000 ? 1 : 0;
            int e = arr ? idx - 2000 : idx;
            int r = e >> 4, cc = e & 15;
            int mb = mc * 125 + r;
            float4 v = *(const float4*)((arr ? Vb : Kb) + (size_t)(bbase + mb) * 64 + cc * 4);
            float* dst = arr ? &Vl[0][0] : &Kl[0][0];
            *(float4*)(dst + r * 64 + cc * 4) = v;
        }
    }

    float4 qf[4][4], fo[4][4];
    float sm[4];
#pragma unroll
    for (int qi = 0; qi < 4; ++qi) {
        int qrow = bbase + min(qloc0 + 16 * qi, NNODES - 1);
        const float4* qp = (const float4*)(Qb + (size_t)qrow * 64 + h * 16);
#pragma unroll
        for (int j = 0; j < 4; ++j) {
            qf[qi][j] = qp[j];
            fo[qi][j] = make_float4(0.f, 0.f, 0.f, 0.f);
        }
        sm[qi] = 0.f;
    }
    __syncthreads();

    for (int mi = 0; mi < 125; ++mi) {
        const float4* kr = (const float4*)(&Kl[mi][h * 16]);
        float4 k0 = kr[0], k1 = kr[1], k2 = kr[2], k3 = kr[3];
        float p[4];
#pragma unroll
        for (int qi = 0; qi < 4; ++qi) {
            float s = D4(qf[qi][0], k0) + D4(qf[qi][1], k1) +
                      D4(qf[qi][2], k2) + D4(qf[qi][3], k3);
            p[qi] = __expf(s);
            sm[qi] += p[qi];
        }
        const float4* vr = (const float4*)(&Vl[mi][h * 16]);
        float4 v0 = vr[0], v1 = vr[1], v2 = vr[2], v3 = vr[3];
#pragma unroll
        for (int qi = 0; qi < 4; ++qi) {
            FMA4(fo[qi][0], p[qi], v0) FMA4(fo[qi][1], p[qi], v1)
            FMA4(fo[qi][2], p[qi], v2) FMA4(fo[qi][3], p[qi], v3)
        }
    }

#pragma unroll
    for (int qi = 0; qi < 4; ++qi) {
        int qloc = qloc0 + 16 * qi;
        if (qloc < NNODES) {
            float* base = Part + (size_t)(mc * 68) * PART_Q + bbase + qloc;
#pragma unroll
            for (int j = 0; j < 4; ++j) {
                base[(size_t)(h * 16 + j * 4 + 0) * PART_Q] = fo[qi][j].x;
                base[(size_t)(h * 16 + j * 4 + 1) * PART_Q] = fo[qi][j].y;
                base[(size_t)(h * 16 + j * 4 + 2) * PART_Q] = fo[qi][j].z;
                base[(size_t)(h * 16 + j * 4 + 3) * PART_Q] = fo[qi][j].w;
            }
            base[(size_t)(64 + h) * PART_Q] = sm[qi];
        }
    }
}

// ---- attn1 merge + out-proj: lane owns q; grid 32 ----
__global__ __launch_bounds__(256) void k_a1m(const float* __restrict__ Part,
        const float* __restrict__ ow, const float* __restrict__ ob,
        float* __restrict__ y1) {
    __shared__ float owl[64][64];
    int tid = threadIdx.x;
    for (int i = tid; i < 4096; i += 256) ((float*)owl)[i] = ow[i];
    __syncthreads();
    int qg = blockIdx.x * 256 + tid;
    if (qg >= PART_Q) return;
    float acc[68];
#pragma unroll
    for (int k = 0; k < 68; ++k) acc[k] = 0.f;
    for (int mc = 0; mc < 16; ++mc) {
        const float* p = Part + (size_t)(mc * 68) * PART_Q + qg;
#pragma unroll
        for (int k = 0; k < 68; ++k) acc[k] += p[(size_t)k * PART_Q];
    }
#pragma unroll
    for (int e = 0; e < 64; ++e) acc[e] /= acc[64 + (e >> 4)];
    float* yo = y1 + (size_t)qg * 64;
    for (int d = 0; d < 64; d += 4) {
        float rr[4];
#pragma unroll
        for (int u = 0; u < 4; ++u) {
            float s = ob[d + u];
            const float4* wr = (const float4*)&owl[d + u][0];
#pragma unroll
            for (int e4 = 0; e4 < 16; ++e4) {
                float4 w4 = wr[e4];
                s = fmaf(acc[e4 * 4 + 0], w4.x, s);
                s = fmaf(acc[e4 * 4 + 1], w4.y, s);
                s = fmaf(acc[e4 * 4 + 2], w4.z, s);
                s = fmaf(acc[e4 * 4 + 3], w4.w, s);
            }
            rr[u] = s;
        }
        *(float4*)(yo + d) = make_float4(rr[0], rr[1], rr[2], rr[3]);
    }
}

// ---- attn2: grid 512 = b4 x qb8 x mc16 (128 m); block 4 waves x 64 q ----
// lane = (c, qs): dim-chunk c, q-slot qs; owns q = qb*256+w*64+qs+16*qi.
// Scores combined across the 4 c-groups with 2 shfl_xor per q per m.
__global__ __launch_bounds__(256, 2) void k_a2(const float* __restrict__ y1,
        const unsigned* __restrict__ maskU, float* __restrict__ Part) {
    __shared__ float Yl[128][64];
    int tid = threadIdx.x, bid = blockIdx.x;
    int b = bid >> 7, qb = (bid >> 4) & 7, mc = bid & 15;
    int bbase = b * NNODES;
    int w = tid >> 6, l = tid & 63;
    int c = l >> 4, qs = l & 15;
    int qloc0 = qb * 256 + w * 64 + qs;

    for (int k = 0; k < 8; ++k) {
        int idx = tid + k * 256;
        int r = idx >> 4, cc = idx & 15;
        int mb = mc * 128 + r;
        float4 v = make_float4(0.f, 0.f, 0.f, 0.f);
        if (mb < NNODES)
            v = *(const float4*)(y1 + (size_t)(bbase + mb) * 64 + cc * 4);
        *(float4*)&Yl[r][cc * 4] = v;
    }

    float4 yq[4][4], fo[4][4];
    float sm[4];
    int qcl[4];
#pragma unroll
    for (int qi = 0; qi < 4; ++qi) {
        qcl[qi] = bbase + min(qloc0 + 16 * qi, NNODES - 1);
        const float4* qp = (const float4*)(y1 + (size_t)qcl[qi] * 64 + c * 16);
#pragma unroll
        for (int j = 0; j < 4; ++j) {
            yq[qi][j] = qp[j];
            fo[qi][j] = make_float4(0.f, 0.f, 0.f, 0.f);
        }
        sm[qi] = 0.f;
    }
    unsigned mw[4] = {0u, 0u, 0u, 0u};
    __syncthreads();

    for (int mi = 0; mi < 128; ++mi) {
        if ((mi & 31) == 0) {
            int wd = mc * 4 + (mi >> 5);
#pragma unroll
            for (int qi = 0; qi < 4; ++qi)
                mw[qi] = maskU[(size_t)wd * PART_Q + qcl[qi]];
        }
        const float4* yr = (const float4*)(&Yl[mi][c * 16]);
        float4 y0 = yr[0], y1v = yr[1], y2 = yr[2], y3 = yr[3];
        float p[4];
#pragma unroll
        for (int qi = 0; qi < 4; ++qi) {
            float s = D4(yq[qi][0], y0) + D4(yq[qi][1], y1v) +
                      D4(yq[qi][2], y2) + D4(yq[qi][3], y3);
            s += __shfl_xor(s, 16, 64);
            s += __shfl_xor(s, 32, 64);
            p[qi] = ((mw[qi] >> (mi & 31)) & 1u) ? __expf(s * 0.125f) : 0.f;
            sm[qi] += p[qi];
        }
#pragma unroll
        for (int qi = 0; qi < 4; ++qi) {
            FMA4(fo[qi][0], p[qi], y0) FMA4(fo[qi][1], p[qi], y1v)
            FMA4(fo[qi][2], p[qi], y2) FMA4(fo[qi][3], p[qi], y3)
        }
    }

#pragma unroll
    for (int qi = 0; qi < 4; ++qi) {
        int qloc = qloc0 + 16 * qi;
        if (qloc < NNODES) {
            float* base = Part + (size_t)(mc * 68) * PART_Q + bbase + qloc;
#pragma unroll
            for (int j = 0; j < 4; ++j) {
                base[(size_t)(c * 16 + j * 4 + 0) * PART_Q] = fo[qi][j].x;
                base[(size_t)(c * 16 + j * 4 + 1) * PART_Q] = fo[qi][j].y;
                base[(size_t)(c * 16 + j * 4 + 2) * PART_Q] = fo[qi][j].z;
                base[(size_t)(c * 16 + j * 4 + 3) * PART_Q] = fo[qi][j].w;
            }
            if (c == 0) base[(size_t)64 * PART_Q] = sm[qi];
        }
    }
}

// ---- attn2 merge: residual + LN + predictor; lane owns q; grid 32 ----
__global__ __launch_bounds__(256) void k_a2m(const float* __restrict__ Part,
        const float* __restrict__ node,
        const float* __restrict__ ga, const float* __restrict__ ba,
        const float* __restrict__ pw, const float* __restrict__ pb,
        float* __restrict__ out) {
    __shared__ float pwl[24][64];
    __shared__ float gal[64], bal[64], pbl[24];
    int tid = threadIdx.x;
    for (int i = tid; i < 24 * 64; i += 256) ((float*)pwl)[i] = pw[i];
    if (tid < 64) { gal[tid] = ga[tid]; bal[tid] = ba[tid]; }
    if (tid < 24) pbl[tid] = pb[tid];
    __syncthreads();
    int qg = blockIdx.x * 256 + tid;
    if (qg >= PART_Q) return;

    float acc[65];
#pragma unroll
    for (int k = 0; k < 65; ++k) acc[k] = 0.f;
    for (int mc = 0; mc < 16; ++mc) {
        const float* p = Part + (size_t)(mc * 68) * PART_Q + qg;
#pragma unroll
        for (int k = 0; k < 65; ++k) acc[k] += p[(size_t)k * PART_Q];
    }
    float inv = 1.0f / acc[64];
    const float* nd = node + (size_t)qg * 64;
    float oo[64];
    float s1 = 0.f, s2 = 0.f;
#pragma unroll
    for (int d = 0; d < 64; ++d) {
        float v = acc[d] * inv + nd[d];
        oo[d] = v;
        s1 += v; s2 += v * v;
    }
    float mu = s1 * (1.f / 64.f);
    float var = s2 * (1.f / 64.f) - mu * mu;
    float rs = rsqrtf(var + 1e-5f);
#pragma unroll
    for (int d = 0; d < 64; ++d) oo[d] = (oo[d] - mu) * rs * gal[d] + bal[d];

    float* op = out + (size_t)qg * HORZ;
    for (int r = 0; r < HORZ; ++r) {
        float s = pbl[r];
        const float4* wr = (const float4*)&pwl[r][0];
#pragma unroll
        for (int e4 = 0; e4 < 16; ++e4) {
            float4 w4 = wr[e4];
            s = fmaf(oo[e4 * 4 + 0], w4.x, s);
            s = fmaf(oo[e4 * 4 + 1], w4.y, s);
            s = fmaf(oo[e4 * 4 + 2], w4.z, s);
            s = fmaf(oo[e4 * 4 + 3], w4.w, s);
        }
        op[r] = s;
    }
}

extern "C" void kernel_launch(void* const* d_in, const int* in_sizes, int n_in,
                              void* d_out, int out_size, void* d_ws, size_t ws_size,
                              hipStream_t stream) {
    const float* x      = (const float*)d_in[0];
    const float* conv_w = (const float*)d_in[1];
    const float* conv_b = (const float*)d_in[2];
    const float* bn_g   = (const float*)d_in[3];
    const float* bn_b   = (const float*)d_in[4];
    const float* proj_w = (const float*)d_in[5];
    const float* proj_b = (const float*)d_in[6];
    const float* ln1_g  = (const float*)d_in[7];
    const float* ln1_b  = (const float*)d_in[8];
    const float* src_w  = (const float*)d_in[9];
    const float* src_b  = (const float*)d_in[10];
    const float* dst_w  = (const float*)d_in[11];
    const float* dst_b  = (const float*)d_in[12];
    const float* edge_s = (const float*)d_in[13];
    const float* ipw    = (const float*)d_in[14];
    const float* ipb    = (const float*)d_in[15];
    const float* out_w  = (const float*)d_in[16];
    const float* out_b  = (const float*)d_in[17];
    const float* lnA_g  = (const float*)d_in[18];
    const float* lnA_b  = (const float*)d_in[19];
    const float* pred_w = (const float*)d_in[20];
    const float* pred_b = (const float*)d_in[21];
    float* out = (float*)d_out;

    float* ws = (float*)d_ws;
    float*    projT = ws;                       //   49152
    float*    node  = projT + 49152;            //  512000
    float*    y1    = node + 512000;            //  512000
    float*    Qb    = y1 + 512000;              //  512000
    float*    Kb    = Qb + 512000;              //  512000
    float*    Vb    = Kb + 512000;              //  512000
    float*    Sbuf  = Vb + 512000;              //  256000
    float*    Dbuf  = Sbuf + 256000;            //  256000
    unsigned* maskU = (unsigned*)(Dbuf + 256000); // 64*8000 u32 = 512000
    float*    ssqP  = (float*)(maskU + 512000); //   32000
    float*    adv   = ssqP + 32000;             //    8000
    float*    Part  = adv + 8000;               // 16*68*8000 = 8704000

    k_tr<<<192, 256, 0, stream>>>(proj_w, projT);
    k_enc<<<1000, 64, 0, stream>>>(x, conv_w, conv_b, bn_g, bn_b,
                                   projT, proj_b, ln1_g, ln1_b, node);
    k_qkv<<<1000, 256, 0, stream>>>(node, ipw, ipb, src_w, src_b, dst_w, dst_b,
                                    Qb, Kb, Vb, Sbuf, Dbuf);
    k_adj<<<512, 256, 0, stream>>>(Sbuf, Dbuf, edge_s, maskU, ssqP, adv);
    k_diag<<<32, 256, 0, stream>>>(ssqP, adv, maskU);
    k_a1<<<512, 256, 0, stream>>>(Qb, Kb, Vb, Part);
    k_a1m<<<32, 256, 0, stream>>>(Part, out_w, out_b, y1);
    k_a2<<<512, 256, 0, stream>>>(y1, maskU, Part);
    k_a2m<<<32, 256, 0, stream>>>(Part, node, lnA_g, lnA_b, pred_w, pred_b, out);
}

// Round 8
// 402.813 us; speedup vs baseline: 1.3140x; 1.3140x over previous
//
#include <hip/hip_runtime.h>
#include <hip/hip_bf16.h>

// DynaGraphNet round 8: attn2 -> MFMA flash kernel (bf16 hi/lo split scores,
// bf16 PV), with q-bit-transposed mask (maskT) built in k_adj and diag folded
// in by k_diag. Everything else (enc/qkv/a1/a1m) byte-identical to round 7.

#define NB 4
#define TT 48
#define NNODES 2000
#define HORZ 24
#define PART_Q 8000

#define D4(a,b) ((a).x*(b).x + (a).y*(b).y + (a).z*(b).z + (a).w*(b).w)
#define FMA4(o,p,v) { (o).x = fmaf((p),(v).x,(o).x); (o).y = fmaf((p),(v).y,(o).y); \
                      (o).z = fmaf((p),(v).z,(o).z); (o).w = fmaf((p),(v).w,(o).w); }

typedef __attribute__((ext_vector_type(8))) short short8;
typedef __attribute__((ext_vector_type(4))) float f32x4;
#define MFMA16(a,b,c) __builtin_amdgcn_mfma_f32_16x16x32_bf16((a),(b),(c),0,0,0)

__device__ __forceinline__ float wsum64(float v) {
#pragma unroll
    for (int m = 1; m < 64; m <<= 1) v += __shfl_xor(v, m, 64);
    return v;
}
__device__ __forceinline__ unsigned short f2bf(float x) {
    unsigned u = __float_as_uint(x);
    unsigned r = (u + 0x7fffu + ((u >> 16) & 1u)) >> 16;
    return (unsigned short)r;
}
__device__ __forceinline__ float bf2f(unsigned short h) {
    return __uint_as_float((unsigned)h << 16);
}

// ---- proj_w [64][768] -> pT4 [jb=192][h=64][4] ----
__global__ __launch_bounds__(256) void k_tr(const float* __restrict__ pw,
                                            float* __restrict__ pT) {
    int i = blockIdx.x * 256 + threadIdx.x;
    int h = i / 768, j = i - h * 768;
    pT[((j >> 2) * 64 + h) * 4 + (j & 3)] = pw[i];
}

// ---- encoder ----
__global__ __launch_bounds__(64) void k_enc(const float* __restrict__ x,
        const float* __restrict__ cw, const float* __restrict__ cb,
        const float* __restrict__ bg, const float* __restrict__ bb,
        const float* __restrict__ pT, const float* __restrict__ pb,
        const float* __restrict__ g1, const float* __restrict__ b1,
        float* __restrict__ node) {
    __shared__ float xs[8][52];
    __shared__ float hs[8][768];
    __shared__ float wc[16][4];
    int tid = threadIdx.x;
    int g0 = blockIdx.x * 8;

    if (tid < 16) {
        float s = bg[tid] * rsqrtf(1.0f + 1e-5f);
        wc[tid][0] = cw[tid * 3 + 0] * s;
        wc[tid][1] = cw[tid * 3 + 1] * s;
        wc[tid][2] = cw[tid * 3 + 2] * s;
        wc[tid][3] = cb[tid] * s + bb[tid];
    }
    for (int i = tid; i < 8 * TT; i += 64) {
        int m = i & 7, t = i >> 3;
        int g = g0 + m;
        int b = g / NNODES, n = g - b * NNODES;
        xs[m][t + 1] = x[(b * TT + t) * NNODES + n];
    }
    if (tid < 8) { xs[tid][0] = 0.f; xs[tid][TT + 1] = 0.f; }
    __syncthreads();

    for (int m = 0; m < 8; m++) {
        for (int j = tid; j < 16 * TT; j += 64) {
            int f = j / TT, t = j - f * TT;
            float h = wc[f][0] * xs[m][t] + wc[f][1] * xs[m][t + 1] +
                      wc[f][2] * xs[m][t + 2] + wc[f][3];
            hs[m][j] = fmaxf(h, 0.f);
        }
    }
    __syncthreads();

    float acc[8];
    float pbv = pb[tid];
#pragma unroll
    for (int m = 0; m < 8; m++) acc[m] = pbv;
    const float4* pT4v = (const float4*)pT;
    for (int jb = 0; jb < 192; ++jb) {
        float4 wv = pT4v[jb * 64 + tid];
#pragma unroll
        for (int m = 0; m < 8; m++) {
            float4 hv = *(const float4*)&hs[m][jb * 4];
            acc[m] += D4(wv, hv);
        }
    }
    float gg = g1[tid], bbv = b1[tid];
    for (int m = 0; m < 8; m++) {
        float v = acc[m];
        float sm = wsum64(v);
        float sq = wsum64(v * v);
        float mu = sm * (1.f / 64.f);
        float var = sq * (1.f / 64.f) - mu * mu;
        float z = (v - mu) * rsqrtf(var + 1e-5f) * gg + bbv;
        node[(g0 + m) * 64 + tid] = fmaxf(z, 0.f);
    }
}

// ---- qkv + src/dst projections ----
__global__ __launch_bounds__(256) void k_qkv(const float* __restrict__ node,
        const float* __restrict__ ipw, const float* __restrict__ ipb,
        const float* __restrict__ sw, const float* __restrict__ sb,
        const float* __restrict__ dw, const float* __restrict__ db,
        float* __restrict__ Qb, float* __restrict__ Kb, float* __restrict__ Vb,
        float* __restrict__ Sb, float* __restrict__ Db) {
    __shared__ float nds[8][64];
    int tid = threadIdx.x;
    int g0 = blockIdx.x * 8;
    for (int i = tid; i < 8 * 64; i += 256) {
        nds[i >> 6][i & 63] = node[(size_t)g0 * 64 + i];
    }
    __syncthreads();

    int o = tid;
    const float* wrow; float bias;
    if (o < 192)      { wrow = ipw + o * 64;          bias = ipb[o]; }
    else if (o < 224) { wrow = sw + (o - 192) * 64;   bias = sb[o - 192]; }
    else              { wrow = dw + (o - 224) * 64;   bias = db[o - 224]; }

    float acc[8];
#pragma unroll
    for (int n = 0; n < 8; ++n) acc[n] = bias;

#pragma unroll
    for (int c = 0; c < 4; ++c) {
        const float4* wp = (const float4*)(wrow + c * 16);
        float4 w0 = wp[0], w1 = wp[1], w2 = wp[2], w3 = wp[3];
#pragma unroll
        for (int n = 0; n < 8; ++n) {
            const float4* nr = (const float4*)&nds[n][c * 16];
            float4 a0 = nr[0], a1 = nr[1], a2 = nr[2], a3 = nr[3];
            acc[n] += D4(a0, w0) + D4(a1, w1) + D4(a2, w2) + D4(a3, w3);
        }
    }

    if (o < 64) {
#pragma unroll
        for (int n = 0; n < 8; ++n) Qb[(size_t)(g0 + n) * 64 + o] = acc[n] * 0.25f;
    } else if (o < 128) {
        int oo = o - 64;
#pragma unroll
        for (int n = 0; n < 8; ++n) Kb[(size_t)(g0 + n) * 64 + oo] = acc[n];
    } else if (o < 192) {
        int oo = o - 128;
#pragma unroll
        for (int n = 0; n < 8; ++n) Vb[(size_t)(g0 + n) * 64 + oo] = acc[n];
    } else if (o < 224) {
        int oo = o - 192;
#pragma unroll
        for (int n = 0; n < 8; ++n) {
            float a = acc[n];
            Sb[(size_t)(g0 + n) * 32 + oo] = (a >= 0.f ? a : 0.2f * a);
        }
    } else {
        int oo = o - 224;
#pragma unroll
        for (int n = 0; n < 8; ++n) {
            float a = acc[n];
            Db[(size_t)(g0 + n) * 32 + oo] = (a >= 0.f ? a : 0.2f * a);
        }
    }
}

// ---- adjacency mask: q-bit-transposed words maskT[(b*64+qw)*2048 + m] ----
__global__ __launch_bounds__(256) void k_adj(const float* __restrict__ Sbuf,
        const float* __restrict__ Dbuf, const float* __restrict__ es_p,
        unsigned* __restrict__ maskT, float* __restrict__ ssqP,
        float* __restrict__ adv) {
    __shared__ float Sl[64][32];
    __shared__ float ssqW[4][64];
    int tid = threadIdx.x, bid = blockIdx.x;
    int b = bid >> 7, qt = (bid >> 2) & 31, mc = bid & 3;
    int w = tid >> 6, l = tid & 63;
    int bbase = b * NNODES;
    int qg0 = bbase + qt * 64;
    float es = es_p[0];

    for (int k = 0; k < 2; ++k) {
        int idx = tid + k * 256;
        int row = idx >> 3, cc = idx & 7;
        int qv = qt * 64 + row;
        *(float4*)&Sl[row][cc * 4] =
            *(const float4*)(Sbuf + (size_t)(bbase + min(qv, NNODES - 1)) * 32 + cc * 4);
    }
    __syncthreads();

    float ssqAcc = 0.f;
#pragma unroll
    for (int tt = 0; tt < 2; ++tt) {
        int t = w + tt * 4;
        int mb = mc * 512 + t * 64 + l;
        bool mok = mb < NNODES;
        float4 dr[8];
        const float4* dp = (const float4*)(Dbuf + (size_t)(bbase + (mok ? mb : NNODES - 1)) * 32);
#pragma unroll
        for (int j = 0; j < 8; ++j) dr[j] = dp[j];

        unsigned long long bits = 0ull;
        for (int qq = 0; qq < 64; ++qq) {
            int qv = qt * 64 + qq;
            const float4* sp = (const float4*)&Sl[qq][0];
            float a = 0.f;
#pragma unroll
            for (int j = 0; j < 8; ++j) a += D4(sp[j], dr[j]);
            a *= es;
            if (!mok) a = 0.f;
            bool diag = (mb == qv);
            if (diag && qv < NNODES) adv[qg0 + qq] = a;
            bits |= ((a > 0.f && !diag) ? 1ull : 0ull) << qq;
            float ssqq = wsum64(a * a);
            if (qq == l) ssqAcc += ssqq;
        }
        maskT[((size_t)(b * 64) + qt * 2) * 2048 + mb] = (unsigned)bits;
        maskT[((size_t)(b * 64) + qt * 2 + 1) * 2048 + mb] = (unsigned)(bits >> 32);
    }
    ssqW[w][l] = ssqAcc;
    __syncthreads();
    if (tid < 64) {
        int qv = qt * 64 + tid;
        if (qv < NNODES)
            ssqP[(size_t)mc * PART_Q + qg0 + tid] =
                ssqW[0][tid] + ssqW[1][tid] + ssqW[2][tid] + ssqW[3][tid];
    }
}

// ---- diag fixup: set maskT bit (q==m) iff ad > -norm ----
__global__ __launch_bounds__(256) void k_diag(const float* __restrict__ ssqP,
        const float* __restrict__ adv, unsigned* __restrict__ maskT) {
    int qg = blockIdx.x * 256 + threadIdx.x;
    if (qg >= PART_Q) return;
    float ss = ssqP[qg] + ssqP[PART_Q + qg] + ssqP[2 * PART_Q + qg] + ssqP[3 * PART_Q + qg];
    float norm = fmaxf(sqrtf(ss), 1e-12f);
    if (adv[qg] > -norm) {
        int b = qg / NNODES, ql = qg - b * NNODES;
        maskT[((size_t)(b * 64) + (ql >> 5)) * 2048 + ql] |= (1u << (ql & 31));
    }
}

// ---- attn1 (unchanged round-7 vector version) ----
__global__ __launch_bounds__(256, 2) void k_a1(const float* __restrict__ Qb,
        const float* __restrict__ Kb, const float* __restrict__ Vb,
        float* __restrict__ Part) {
    __shared__ float Kl[125][64];
    __shared__ float Vl[125][64];
    int tid = threadIdx.x, bid = blockIdx.x;
    int b = bid >> 7, qb = (bid >> 4) & 7, mc = bid & 15;
    int bbase = b * NNODES;
    int w = tid >> 6, l = tid & 63;
    int h = l >> 4, qs = l & 15;
    int qloc0 = qb * 256 + w * 64 + qs;

    for (int k = 0; k < 16; ++k) {
        int idx = tid + k * 256;
        if (idx < 4000) {
            int arr = idx >= 2000 ? 1 : 0;
            int e = arr ? idx - 2000 : idx;
            int r = e >> 4, cc = e & 15;
            int mb = mc * 125 + r;
            float4 v = *(const float4*)((arr ? Vb : Kb) + (size_t)(bbase + mb) * 64 + cc * 4);
            float* dst = arr ? &Vl[0][0] : &Kl[0][0];
            *(float4*)(dst + r * 64 + cc * 4) = v;
        }
    }

    float4 qf[4][4], fo[4][4];
    float sm[4];
#pragma unroll
    for (int qi = 0; qi < 4; ++qi) {
        int qrow = bbase + min(qloc0 + 16 * qi, NNODES - 1);
        const float4* qp = (const float4*)(Qb + (size_t)qrow * 64 + h * 16);
#pragma unroll
        for (int j = 0; j < 4; ++j) {
            qf[qi][j] = qp[j];
            fo[qi][j] = make_float4(0.f, 0.f, 0.f, 0.f);
        }
        sm[qi] = 0.f;
    }
    __syncthreads();

    for (int mi = 0; mi < 125; ++mi) {
        const float4* kr = (const float4*)(&Kl[mi][h * 16]);
        float4 k0 = kr[0], k1 = kr[1], k2 = kr[2], k3 = kr[3];
        float p[4];
#pragma unroll
        for (int qi = 0; qi < 4; ++qi) {
            float s = D4(qf[qi][0], k0) + D4(qf[qi][1], k1) +
                      D4(qf[qi][2], k2) + D4(qf[qi][3], k3);
            p[qi] = __expf(s);
            sm[qi] += p[qi];
        }
        const float4* vr = (const float4*)(&Vl[mi][h * 16]);
        float4 v0 = vr[0], v1 = vr[1], v2 = vr[2], v3 = vr[3];
#pragma unroll
        for (int qi = 0; qi < 4; ++qi) {
            FMA4(fo[qi][0], p[qi], v0) FMA4(fo[qi][1], p[qi], v1)
            FMA4(fo[qi][2], p[qi], v2) FMA4(fo[qi][3], p[qi], v3)
        }
    }

#pragma unroll
    for (int qi = 0; qi < 4; ++qi) {
        int qloc = qloc0 + 16 * qi;
        if (qloc < NNODES) {
            float* base = Part + (size_t)(mc * 68) * PART_Q + bbase + qloc;
#pragma unroll
            for (int j = 0; j < 4; ++j) {
                base[(size_t)(h * 16 + j * 4 + 0) * PART_Q] = fo[qi][j].x;
                base[(size_t)(h * 16 + j * 4 + 1) * PART_Q] = fo[qi][j].y;
                base[(size_t)(h * 16 + j * 4 + 2) * PART_Q] = fo[qi][j].z;
                base[(size_t)(h * 16 + j * 4 + 3) * PART_Q] = fo[qi][j].w;
            }
            base[(size_t)(64 + h) * PART_Q] = sm[qi];
        }
    }
}

// ---- attn1 merge + out-proj (unchanged) ----
__global__ __launch_bounds__(256) void k_a1m(const float* __restrict__ Part,
        const float* __restrict__ ow, const float* __restrict__ ob,
        float* __restrict__ y1) {
    __shared__ float owl[64][64];
    int tid = threadIdx.x;
    for (int i = tid; i < 4096; i += 256) ((float*)owl)[i] = ow[i];
    __syncthreads();
    int qg = blockIdx.x * 256 + tid;
    if (qg >= PART_Q) return;
    float acc[68];
#pragma unroll
    for (int k = 0; k < 68; ++k) acc[k] = 0.f;
    for (int mc = 0; mc < 16; ++mc) {
        const float* p = Part + (size_t)(mc * 68) * PART_Q + qg;
#pragma unroll
        for (int k = 0; k < 68; ++k) acc[k] += p[(size_t)k * PART_Q];
    }
#pragma unroll
    for (int e = 0; e < 64; ++e) acc[e] /= acc[64 + (e >> 4)];
    float* yo = y1 + (size_t)qg * 64;
    for (int d = 0; d < 64; d += 4) {
        float rr[4];
#pragma unroll
        for (int u = 0; u < 4; ++u) {
            float s = ob[d + u];
            const float4* wr = (const float4*)&owl[d + u][0];
#pragma unroll
            for (int e4 = 0; e4 < 16; ++e4) {
                float4 w4 = wr[e4];
                s = fmaf(acc[e4 * 4 + 0], w4.x, s);
                s = fmaf(acc[e4 * 4 + 1], w4.y, s);
                s = fmaf(acc[e4 * 4 + 2], w4.z, s);
                s = fmaf(acc[e4 * 4 + 3], w4.w, s);
            }
            rr[u] = s;
        }
        *(float4*)(yo + d) = make_float4(rr[0], rr[1], rr[2], rr[3]);
    }
}

// ---- attn2 MFMA flash: grid 1024 = b4 x qt32 x mc8; 4 waves x 16-q tiles ----
// Per 64-m step: stage Y hi/lo bf16 row-major + hi transposed; scores =
// 3-pass split mfma (hi.hi + lo.hi + hi.lo); mask from maskT; p->bf16 to LDS
// P-tile (C->A relayout); PV = 8 mfma. Partial (o,sum) per (mc,q) to Part.
__global__ __launch_bounds__(256, 2) void k_a2(const float* __restrict__ y1,
        const unsigned* __restrict__ maskTg, float* __restrict__ Part) {
    __shared__ unsigned short Yhi[64 * 72];
    __shared__ unsigned short Ylo[64 * 72];
    __shared__ unsigned short Yt[64 * 72];
    __shared__ unsigned short Pl[4 * 16 * 72];
    __shared__ unsigned maskTl[2 * 256];

    int tid = threadIdx.x, bid = blockIdx.x;
    int b = bid >> 8, qt = (bid >> 3) & 31, mc = bid & 7;
    int wv = tid >> 6, l = tid & 63;
    int l15 = l & 15, lg = l >> 4;
    const float* y1b = y1 + (size_t)(b * NNODES) * 64;

    // stage mask words for this block's two q-words
    for (int i = tid; i < 512; i += 256) {
        int wq = i >> 8, ml = i & 255;
        int mg = mc * 256 + ml;
        maskTl[wq * 256 + ml] =
            (mg < NNODES) ? maskTg[((size_t)(b * 64) + qt * 2 + wq) * 2048 + mg] : 0u;
    }

    // q-side A-fragments (hi/lo), fixed for the whole m-loop
    int qloc_f = min(qt * 64 + wv * 16 + l15, NNODES - 1);
    const float* qrow = y1b + (size_t)qloc_f * 64;
    short8 Ahi0, Ahi1, Alo0, Alo1;
#pragma unroll
    for (int j = 0; j < 8; ++j) {
        float x0 = qrow[lg * 8 + j];
        unsigned short h0 = f2bf(x0);
        Ahi0[j] = (short)h0; Alo0[j] = (short)f2bf(x0 - bf2f(h0));
        float x1 = qrow[32 + lg * 8 + j];
        unsigned short h1 = f2bf(x1);
        Ahi1[j] = (short)h1; Alo1[j] = (short)f2bf(x1 - bf2f(h1));
    }

    f32x4 O0 = {0.f,0.f,0.f,0.f}, O1 = {0.f,0.f,0.f,0.f};
    f32x4 O2 = {0.f,0.f,0.f,0.f}, O3 = {0.f,0.f,0.f,0.f};
    float sumAcc[4] = {0.f, 0.f, 0.f, 0.f};
    int wvbase = wv * 16 * 72;
    int bitb = (wv & 1) * 16 + lg * 4;
    int mword = wv >> 1;

    for (int step = 0; step < 4; ++step) {
        int m0 = mc * 256 + step * 64;
        // stage 64 m-rows: hi/lo row-major + hi transposed
        for (int i = tid; i < 1024; i += 256) {
            int r = i >> 4, c4 = i & 15;
            int mg = m0 + r;
            float4 v = make_float4(0.f, 0.f, 0.f, 0.f);
            if (mg < NNODES) v = *(const float4*)(y1b + (size_t)mg * 64 + c4 * 4);
            unsigned short h0 = f2bf(v.x), h1 = f2bf(v.y), h2 = f2bf(v.z), h3 = f2bf(v.w);
            ushort4 hv = {h0, h1, h2, h3};
            *(ushort4*)&Yhi[r * 72 + c4 * 4] = hv;
            ushort4 lv = {f2bf(v.x - bf2f(h0)), f2bf(v.y - bf2f(h1)),
                          f2bf(v.z - bf2f(h2)), f2bf(v.w - bf2f(h3))};
            *(ushort4*)&Ylo[r * 72 + c4 * 4] = lv;
            Yt[(c4 * 4 + 0) * 72 + r] = h0;
            Yt[(c4 * 4 + 1) * 72 + r] = h1;
            Yt[(c4 * 4 + 2) * 72 + r] = h2;
            Yt[(c4 * 4 + 3) * 72 + r] = h3;
        }
        __syncthreads();

        // scores + mask + exp + P-tile
#pragma unroll
        for (int mt = 0; mt < 4; ++mt) {
            int mrow = mt * 16 + l15;
            short8 bh0 = *(const short8*)&Yhi[mrow * 72 + lg * 8];
            short8 bh1 = *(const short8*)&Yhi[mrow * 72 + 32 + lg * 8];
            short8 bl0 = *(const short8*)&Ylo[mrow * 72 + lg * 8];
            short8 bl1 = *(const short8*)&Ylo[mrow * 72 + 32 + lg * 8];
            f32x4 S = {0.f, 0.f, 0.f, 0.f};
            S = MFMA16(Ahi0, bh0, S); S = MFMA16(Ahi1, bh1, S);
            S = MFMA16(Alo0, bh0, S); S = MFMA16(Alo1, bh1, S);
            S = MFMA16(Ahi0, bl0, S); S = MFMA16(Ahi1, bl1, S);
            unsigned mwv = maskTl[mword * 256 + step * 64 + mt * 16 + l15];
#pragma unroll
            for (int r = 0; r < 4; ++r) {
                float p = ((mwv >> (bitb + r)) & 1u) ? __expf(S[r] * 0.125f) : 0.f;
                sumAcc[r] += p;
                Pl[wvbase + (lg * 4 + r) * 72 + mt * 16 + l15] = f2bf(p);
            }
        }

        // PV: O[16q x 64d] += P[16 x 64] * Yhi[64 x 64]
#pragma unroll
        for (int ks = 0; ks < 2; ++ks) {
            short8 pf = *(const short8*)&Pl[wvbase + l15 * 72 + ks * 32 + lg * 8];
            short8 v0 = *(const short8*)&Yt[(0 * 16 + l15) * 72 + ks * 32 + lg * 8];
            O0 = MFMA16(pf, v0, O0);
            short8 v1 = *(const short8*)&Yt[(1 * 16 + l15) * 72 + ks * 32 + lg * 8];
            O1 = MFMA16(pf, v1, O1);
            short8 v2 = *(const short8*)&Yt[(2 * 16 + l15) * 72 + ks * 32 + lg * 8];
            O2 = MFMA16(pf, v2, O2);
            short8 v3 = *(const short8*)&Yt[(3 * 16 + l15) * 72 + ks * 32 + lg * 8];
            O3 = MFMA16(pf, v3, O3);
        }
        __syncthreads();
    }

    // reduce sums over the 16 m-lanes in each group
#pragma unroll
    for (int r = 0; r < 4; ++r) {
        float s = sumAcc[r];
        s += __shfl_xor(s, 1, 64); s += __shfl_xor(s, 2, 64);
        s += __shfl_xor(s, 4, 64); s += __shfl_xor(s, 8, 64);
        sumAcc[r] = s;
    }
    // write partials: Part[(mc*8192 + b*2048 + qloc)*72 + {d:0..63, 64:sum}]
    int qrow_base = qt * 64 + wv * 16 + lg * 4;
#pragma unroll
    for (int r = 0; r < 4; ++r) {
        int qloc = qrow_base + r;
        if (qloc < NNODES) {
            float* pp = Part + ((size_t)(mc * 8192) + b * 2048 + qloc) * 72;
            pp[0 * 16 + l15] = O0[r];
            pp[1 * 16 + l15] = O1[r];
            pp[2 * 16 + l15] = O2[r];
            pp[3 * 16 + l15] = O3[r];
            if (l15 == 0) pp[64] = sumAcc[r];
        }
    }
}

// ---- attn2 merge: sum chunks + residual + LN + predictor ----
__global__ __launch_bounds__(256) void k_a2m(const float* __restrict__ Part,
        const float* __restrict__ node,
        const float* __restrict__ ga, const float* __restrict__ ba,
        const float* __restrict__ pw, const float* __restrict__ pb,
        float* __restrict__ out) {
    __shared__ float pwl[24 * 64];
    __shared__ float gal[64], bal[64], pbl[24];
    int tid = threadIdx.x;
    for (int i = tid; i < 24 * 64; i += 256) pwl[i] = pw[i];
    if (tid < 64) { gal[tid] = ga[tid]; bal[tid] = ba[tid]; }
    if (tid < 24) pbl[tid] = pb[tid];
    __syncthreads();
    int t = blockIdx.x * 256 + tid;        // 0..8191
    int b = t >> 11, ql = t & 2047;
    if (ql >= NNODES) return;
    int qg = b * NNODES + ql;

    float acc[65];
#pragma unroll
    for (int k = 0; k < 65; ++k) acc[k] = 0.f;
    for (int mc = 0; mc < 8; ++mc) {
        const float* p = Part + ((size_t)(mc * 8192) + b * 2048 + ql) * 72;
#pragma unroll
        for (int k = 0; k < 65; ++k) acc[k] += p[k];
    }
    float inv = 1.0f / acc[64];
    const float* nd = node + (size_t)qg * 64;
    float oo[64];
    float s1 = 0.f, s2 = 0.f;
#pragma unroll
    for (int d = 0; d < 64; ++d) {
        float v = acc[d] * inv + nd[d];
        oo[d] = v;
        s1 += v; s2 += v * v;
    }
    float mu = s1 * (1.f / 64.f);
    float var = s2 * (1.f / 64.f) - mu * mu;
    float rs = rsqrtf(var + 1e-5f);
#pragma unroll
    for (int d = 0; d < 64; ++d) oo[d] = (oo[d] - mu) * rs * gal[d] + bal[d];

    float* op = out + (size_t)qg * HORZ;
    for (int r = 0; r < HORZ; ++r) {
        float s = pbl[r];
        const float4* wr = (const float4*)&pwl[r * 64];
#pragma unroll
        for (int e4 = 0; e4 < 16; ++e4) {
            float4 w4 = wr[e4];
            s = fmaf(oo[e4 * 4 + 0], w4.x, s);
            s = fmaf(oo[e4 * 4 + 1], w4.y, s);
            s = fmaf(oo[e4 * 4 + 2], w4.z, s);
            s = fmaf(oo[e4 * 4 + 3], w4.w, s);
        }
        op[r] = s;
    }
}

extern "C" void kernel_launch(void* const* d_in, const int* in_sizes, int n_in,
                              void* d_out, int out_size, void* d_ws, size_t ws_size,
                              hipStream_t stream) {
    const float* x      = (const float*)d_in[0];
    const float* conv_w = (const float*)d_in[1];
    const float* conv_b = (const float*)d_in[2];
    const float* bn_g   = (const float*)d_in[3];
    const float* bn_b   = (const float*)d_in[4];
    const float* proj_w = (const float*)d_in[5];
    const float* proj_b = (const float*)d_in[6];
    const float* ln1_g  = (const float*)d_in[7];
    const float* ln1_b  = (const float*)d_in[8];
    const float* src_w  = (const float*)d_in[9];
    const float* src_b  = (const float*)d_in[10];
    const float* dst_w  = (const float*)d_in[11];
    const float* dst_b  = (const float*)d_in[12];
    const float* edge_s = (const float*)d_in[13];
    const float* ipw    = (const float*)d_in[14];
    const float* ipb    = (const float*)d_in[15];
    const float* out_w  = (const float*)d_in[16];
    const float* out_b  = (const float*)d_in[17];
    const float* lnA_g  = (const float*)d_in[18];
    const float* lnA_b  = (const float*)d_in[19];
    const float* pred_w = (const float*)d_in[20];
    const float* pred_b = (const float*)d_in[21];
    float* out = (float*)d_out;

    float* ws = (float*)d_ws;
    float*    projT = ws;                         //   49152
    float*    node  = projT + 49152;              //  512000
    float*    y1    = node + 512000;              //  512000
    float*    Qb    = y1 + 512000;                //  512000
    float*    Kb    = Qb + 512000;                //  512000
    float*    Vb    = Kb + 512000;                //  512000
    float*    Sbuf  = Vb + 512000;                //  256000
    float*    Dbuf  = Sbuf + 256000;              //  256000
    unsigned* maskT = (unsigned*)(Dbuf + 256000); // 4*64*2048 = 524288 u32
    float*    ssqP  = (float*)(maskT + 524288);   //   32000
    float*    adv   = ssqP + 32000;               //    8000
    float*    Part  = adv + 8000;                 // 8704000 (a1 old layout; a2 uses 4.72M)

    k_tr<<<192, 256, 0, stream>>>(proj_w, projT);
    k_enc<<<1000, 64, 0, stream>>>(x, conv_w, conv_b, bn_g, bn_b,
                                   projT, proj_b, ln1_g, ln1_b, node);
    k_qkv<<<1000, 256, 0, stream>>>(node, ipw, ipb, src_w, src_b, dst_w, dst_b,
                                    Qb, Kb, Vb, Sbuf, Dbuf);
    k_adj<<<512, 256, 0, stream>>>(Sbuf, Dbuf, edge_s, maskT, ssqP, adv);
    k_diag<<<32, 256, 0, stream>>>(ssqP, adv, maskT);
    k_a1<<<512, 256, 0, stream>>>(Qb, Kb, Vb, Part);
    k_a1m<<<32, 256, 0, stream>>>(Part, out_w, out_b, y1);
    k_a2<<<1024, 256, 0, stream>>>(y1, maskT, Part);
    k_a2m<<<32, 256, 0, stream>>>(Part, node, lnA_g, lnA_b, pred_w, pred_b, out);
}

// Round 10
// 368.565 us; speedup vs baseline: 1.4360x; 1.0929x over previous
//
#include <hip/hip_runtime.h>
#include <hip/hip_bf16.h>

// DynaGraphNet round 10 = round 9 resubmitted verbatim (round 9 bench died on
// GPU acquisition timeout — no measurement). k_a1 -> MFMA flash kernel
// (per-head padded-K bf16 hi/lo scores, head-by-head P-tile PV). k_a2 MFMA
// (round 8, verified) unchanged. enc/qkv/adj/diag/a2m byte-identical.

#define NB 4
#define TT 48
#define NNODES 2000
#define HORZ 24
#define PART_Q 8000

#define D4(a,b) ((a).x*(b).x + (a).y*(b).y + (a).z*(b).z + (a).w*(b).w)

typedef __attribute__((ext_vector_type(8))) short short8;
typedef __attribute__((ext_vector_type(4))) float f32x4;
#define MFMA16(a,b,c) __builtin_amdgcn_mfma_f32_16x16x32_bf16((a),(b),(c),0,0,0)

__device__ __forceinline__ float wsum64(float v) {
#pragma unroll
    for (int m = 1; m < 64; m <<= 1) v += __shfl_xor(v, m, 64);
    return v;
}
__device__ __forceinline__ unsigned short f2bf(float x) {
    unsigned u = __float_as_uint(x);
    unsigned r = (u + 0x7fffu + ((u >> 16) & 1u)) >> 16;
    return (unsigned short)r;
}
__device__ __forceinline__ float bf2f(unsigned short h) {
    return __uint_as_float((unsigned)h << 16);
}

// ---- proj_w [64][768] -> pT4 [jb=192][h=64][4] ----
__global__ __launch_bounds__(256) void k_tr(const float* __restrict__ pw,
                                            float* __restrict__ pT) {
    int i = blockIdx.x * 256 + threadIdx.x;
    int h = i / 768, j = i - h * 768;
    pT[((j >> 2) * 64 + h) * 4 + (j & 3)] = pw[i];
}

// ---- encoder ----
__global__ __launch_bounds__(64) void k_enc(const float* __restrict__ x,
        const float* __restrict__ cw, const float* __restrict__ cb,
        const float* __restrict__ bg, const float* __restrict__ bb,
        const float* __restrict__ pT, const float* __restrict__ pb,
        const float* __restrict__ g1, const float* __restrict__ b1,
        float* __restrict__ node) {
    __shared__ float xs[8][52];
    __shared__ float hs[8][768];
    __shared__ float wc[16][4];
    int tid = threadIdx.x;
    int g0 = blockIdx.x * 8;

    if (tid < 16) {
        float s = bg[tid] * rsqrtf(1.0f + 1e-5f);
        wc[tid][0] = cw[tid * 3 + 0] * s;
        wc[tid][1] = cw[tid * 3 + 1] * s;
        wc[tid][2] = cw[tid * 3 + 2] * s;
        wc[tid][3] = cb[tid] * s + bb[tid];
    }
    for (int i = tid; i < 8 * TT; i += 64) {
        int m = i & 7, t = i >> 3;
        int g = g0 + m;
        int b = g / NNODES, n = g - b * NNODES;
        xs[m][t + 1] = x[(b * TT + t) * NNODES + n];
    }
    if (tid < 8) { xs[tid][0] = 0.f; xs[tid][TT + 1] = 0.f; }
    __syncthreads();

    for (int m = 0; m < 8; m++) {
        for (int j = tid; j < 16 * TT; j += 64) {
            int f = j / TT, t = j - f * TT;
            float h = wc[f][0] * xs[m][t] + wc[f][1] * xs[m][t + 1] +
                      wc[f][2] * xs[m][t + 2] + wc[f][3];
            hs[m][j] = fmaxf(h, 0.f);
        }
    }
    __syncthreads();

    float acc[8];
    float pbv = pb[tid];
#pragma unroll
    for (int m = 0; m < 8; m++) acc[m] = pbv;
    const float4* pT4v = (const float4*)pT;
    for (int jb = 0; jb < 192; ++jb) {
        float4 wv = pT4v[jb * 64 + tid];
#pragma unroll
        for (int m = 0; m < 8; m++) {
            float4 hv = *(const float4*)&hs[m][jb * 4];
            acc[m] += D4(wv, hv);
        }
    }
    float gg = g1[tid], bbv = b1[tid];
    for (int m = 0; m < 8; m++) {
        float v = acc[m];
        float sm = wsum64(v);
        float sq = wsum64(v * v);
        float mu = sm * (1.f / 64.f);
        float var = sq * (1.f / 64.f) - mu * mu;
        float z = (v - mu) * rsqrtf(var + 1e-5f) * gg + bbv;
        node[(g0 + m) * 64 + tid] = fmaxf(z, 0.f);
    }
}

// ---- qkv + src/dst projections ----
__global__ __launch_bounds__(256) void k_qkv(const float* __restrict__ node,
        const float* __restrict__ ipw, const float* __restrict__ ipb,
        const float* __restrict__ sw, const float* __restrict__ sb,
        const float* __restrict__ dw, const float* __restrict__ db,
        float* __restrict__ Qb, float* __restrict__ Kb, float* __restrict__ Vb,
        float* __restrict__ Sb, float* __restrict__ Db) {
    __shared__ float nds[8][64];
    int tid = threadIdx.x;
    int g0 = blockIdx.x * 8;
    for (int i = tid; i < 8 * 64; i += 256) {
        nds[i >> 6][i & 63] = node[(size_t)g0 * 64 + i];
    }
    __syncthreads();

    int o = tid;
    const float* wrow; float bias;
    if (o < 192)      { wrow = ipw + o * 64;          bias = ipb[o]; }
    else if (o < 224) { wrow = sw + (o - 192) * 64;   bias = sb[o - 192]; }
    else              { wrow = dw + (o - 224) * 64;   bias = db[o - 224]; }

    float acc[8];
#pragma unroll
    for (int n = 0; n < 8; ++n) acc[n] = bias;

#pragma unroll
    for (int c = 0; c < 4; ++c) {
        const float4* wp = (const float4*)(wrow + c * 16);
        float4 w0 = wp[0], w1 = wp[1], w2 = wp[2], w3 = wp[3];
#pragma unroll
        for (int n = 0; n < 8; ++n) {
            const float4* nr = (const float4*)&nds[n][c * 16];
            float4 a0 = nr[0], a1 = nr[1], a2 = nr[2], a3 = nr[3];
            acc[n] += D4(a0, w0) + D4(a1, w1) + D4(a2, w2) + D4(a3, w3);
        }
    }

    if (o < 64) {
#pragma unroll
        for (int n = 0; n < 8; ++n) Qb[(size_t)(g0 + n) * 64 + o] = acc[n] * 0.25f;
    } else if (o < 128) {
        int oo = o - 64;
#pragma unroll
        for (int n = 0; n < 8; ++n) Kb[(size_t)(g0 + n) * 64 + oo] = acc[n];
    } else if (o < 192) {
        int oo = o - 128;
#pragma unroll
        for (int n = 0; n < 8; ++n) Vb[(size_t)(g0 + n) * 64 + oo] = acc[n];
    } else if (o < 224) {
        int oo = o - 192;
#pragma unroll
        for (int n = 0; n < 8; ++n) {
            float a = acc[n];
            Sb[(size_t)(g0 + n) * 32 + oo] = (a >= 0.f ? a : 0.2f * a);
        }
    } else {
        int oo = o - 224;
#pragma unroll
        for (int n = 0; n < 8; ++n) {
            float a = acc[n];
            Db[(size_t)(g0 + n) * 32 + oo] = (a >= 0.f ? a : 0.2f * a);
        }
    }
}

// ---- adjacency mask: q-bit-transposed words maskT[(b*64+qw)*2048 + m] ----
__global__ __launch_bounds__(256) void k_adj(const float* __restrict__ Sbuf,
        const float* __restrict__ Dbuf, const float* __restrict__ es_p,
        unsigned* __restrict__ maskT, float* __restrict__ ssqP,
        float* __restrict__ adv) {
    __shared__ float Sl[64][32];
    __shared__ float ssqW[4][64];
    int tid = threadIdx.x, bid = blockIdx.x;
    int b = bid >> 7, qt = (bid >> 2) & 31, mc = bid & 3;
    int w = tid >> 6, l = tid & 63;
    int bbase = b * NNODES;
    int qg0 = bbase + qt * 64;
    float es = es_p[0];

    for (int k = 0; k < 2; ++k) {
        int idx = tid + k * 256;
        int row = idx >> 3, cc = idx & 7;
        int qv = qt * 64 + row;
        *(float4*)&Sl[row][cc * 4] =
            *(const float4*)(Sbuf + (size_t)(bbase + min(qv, NNODES - 1)) * 32 + cc * 4);
    }
    __syncthreads();

    float ssqAcc = 0.f;
#pragma unroll
    for (int tt = 0; tt < 2; ++tt) {
        int t = w + tt * 4;
        int mb = mc * 512 + t * 64 + l;
        bool mok = mb < NNODES;
        float4 dr[8];
        const float4* dp = (const float4*)(Dbuf + (size_t)(bbase + (mok ? mb : NNODES - 1)) * 32);
#pragma unroll
        for (int j = 0; j < 8; ++j) dr[j] = dp[j];

        unsigned long long bits = 0ull;
        for (int qq = 0; qq < 64; ++qq) {
            int qv = qt * 64 + qq;
            const float4* sp = (const float4*)&Sl[qq][0];
            float a = 0.f;
#pragma unroll
            for (int j = 0; j < 8; ++j) a += D4(sp[j], dr[j]);
            a *= es;
            if (!mok) a = 0.f;
            bool diag = (mb == qv);
            if (diag && qv < NNODES) adv[qg0 + qq] = a;
            bits |= ((a > 0.f && !diag) ? 1ull : 0ull) << qq;
            float ssqq = wsum64(a * a);
            if (qq == l) ssqAcc += ssqq;
        }
        maskT[((size_t)(b * 64) + qt * 2) * 2048 + mb] = (unsigned)bits;
        maskT[((size_t)(b * 64) + qt * 2 + 1) * 2048 + mb] = (unsigned)(bits >> 32);
    }
    ssqW[w][l] = ssqAcc;
    __syncthreads();
    if (tid < 64) {
        int qv = qt * 64 + tid;
        if (qv < NNODES)
            ssqP[(size_t)mc * PART_Q + qg0 + tid] =
                ssqW[0][tid] + ssqW[1][tid] + ssqW[2][tid] + ssqW[3][tid];
    }
}

// ---- diag fixup ----
__global__ __launch_bounds__(256) void k_diag(const float* __restrict__ ssqP,
        const float* __restrict__ adv, unsigned* __restrict__ maskT) {
    int qg = blockIdx.x * 256 + threadIdx.x;
    if (qg >= PART_Q) return;
    float ss = ssqP[qg] + ssqP[PART_Q + qg] + ssqP[2 * PART_Q + qg] + ssqP[3 * PART_Q + qg];
    float norm = fmaxf(sqrtf(ss), 1e-12f);
    if (adv[qg] > -norm) {
        int b = qg / NNODES, ql = qg - b * NNODES;
        maskT[((size_t)(b * 64) + (ql >> 5)) * 2048 + ql] |= (1u << (ql & 31));
    }
}

// ---- attn1 MFMA flash: grid 1024 = b4 x qt32 x mc8; 4 waves x 16-q tiles ----
// Per head h: S_h = Q_h.K_h^T via padded-K: mfma(A=[Qhi|Qlo],B=[Khi|Khi]) +
// mfma(A=[Qhi|0],B=[Klo|0]). exp (pad rows p=0), P_h bf16 -> LDS, PV 2 mfma.
__global__ __launch_bounds__(256, 2) void k_a1(const float* __restrict__ Qb,
        const float* __restrict__ Kb, const float* __restrict__ Vb,
        float* __restrict__ Part) {
    __shared__ unsigned short Khi[64 * 72];
    __shared__ unsigned short Klo[64 * 72];
    __shared__ unsigned short Vt[64 * 73];
    __shared__ unsigned short Pl[4 * 16 * 72];

    int tid = threadIdx.x, bid = blockIdx.x;
    int b = bid >> 8, qt = (bid >> 3) & 31, mc = bid & 7;
    int bbase = b * NNODES;
    int wv = tid >> 6, l = tid & 63;
    int l15 = l & 15, lg = l >> 4;
    bool hiSel = (lg < 2);
    int dof = (lg & 1) * 8;

    // per-lane Q A-fragments (4 heads), fixed all m
    int qloc_f = min(qt * 64 + wv * 16 + l15, NNODES - 1);
    const float* qrow = Qb + (size_t)(bbase + qloc_f) * 64;
    short8 A1[4], A2[4];
#pragma unroll
    for (int h = 0; h < 4; ++h) {
#pragma unroll
        for (int j = 0; j < 8; ++j) {
            float v = qrow[h * 16 + dof + j];
            unsigned short hv = f2bf(v);
            unsigned short lv = f2bf(v - bf2f(hv));
            A1[h][j] = (short)(hiSel ? hv : lv);
            A2[h][j] = (short)(hiSel ? hv : 0);
        }
    }

    f32x4 O[4];
#pragma unroll
    for (int h = 0; h < 4; ++h) O[h] = (f32x4){0.f, 0.f, 0.f, 0.f};
    float sumAcc[16];
#pragma unroll
    for (int i = 0; i < 16; ++i) sumAcc[i] = 0.f;
    short8 zz = {0, 0, 0, 0, 0, 0, 0, 0};
    int plb = wv * 1152;

    for (int step = 0; step < 4; ++step) {
        int m0 = mc * 256 + step * 64;
        for (int i = tid; i < 1024; i += 256) {       // K rows -> hi/lo
            int r = i >> 4, c4 = i & 15;
            int mg = m0 + r;
            float4 v = make_float4(0.f, 0.f, 0.f, 0.f);
            if (mg < NNODES) v = *(const float4*)(Kb + (size_t)(bbase + mg) * 64 + c4 * 4);
            unsigned short h0 = f2bf(v.x), h1 = f2bf(v.y), h2 = f2bf(v.z), h3 = f2bf(v.w);
            ushort4 hv = {h0, h1, h2, h3};
            *(ushort4*)&Khi[r * 72 + c4 * 4] = hv;
            ushort4 lv = {f2bf(v.x - bf2f(h0)), f2bf(v.y - bf2f(h1)),
                          f2bf(v.z - bf2f(h2)), f2bf(v.w - bf2f(h3))};
            *(ushort4*)&Klo[r * 72 + c4 * 4] = lv;
        }
        for (int i = tid; i < 1024; i += 256) {       // V rows -> Vt (hi)
            int r = i >> 4, c4 = i & 15;
            int mg = m0 + r;
            float4 v = make_float4(0.f, 0.f, 0.f, 0.f);
            if (mg < NNODES) v = *(const float4*)(Vb + (size_t)(bbase + mg) * 64 + c4 * 4);
            Vt[(c4 * 4 + 0) * 73 + r] = f2bf(v.x);
            Vt[(c4 * 4 + 1) * 73 + r] = f2bf(v.y);
            Vt[(c4 * 4 + 2) * 73 + r] = f2bf(v.z);
            Vt[(c4 * 4 + 3) * 73 + r] = f2bf(v.w);
        }
        __syncthreads();

#pragma unroll
        for (int h = 0; h < 4; ++h) {
#pragma unroll
            for (int mt = 0; mt < 4; ++mt) {
                int mrow = mt * 16 + l15;
                short8 b1 = *(const short8*)&Khi[mrow * 72 + h * 16 + dof];
                short8 b2 = *(const short8*)&Klo[mrow * 72 + h * 16 + dof];
                if (!hiSel) b2 = zz;
                f32x4 S = {0.f, 0.f, 0.f, 0.f};
                S = MFMA16(A1[h], b1, S);
                S = MFMA16(A2[h], b2, S);
                int mglob = m0 + mrow;
#pragma unroll
                for (int r = 0; r < 4; ++r) {
                    float p = (mglob < NNODES) ? __expf(S[r]) : 0.f;
                    sumAcc[h * 4 + r] += p;
                    Pl[plb + (lg * 4 + r) * 72 + mrow] = f2bf(p);
                }
            }
#pragma unroll
            for (int ks = 0; ks < 2; ++ks) {
                short8 pf = *(const short8*)&Pl[plb + l15 * 72 + ks * 32 + lg * 8];
                short8 vf = *(const short8*)&Vt[(h * 16 + l15) * 73 + ks * 32 + lg * 8];
                O[h] = MFMA16(pf, vf, O[h]);
            }
        }
        __syncthreads();
    }

#pragma unroll
    for (int i = 0; i < 16; ++i) {
        float s = sumAcc[i];
        s += __shfl_xor(s, 1, 64); s += __shfl_xor(s, 2, 64);
        s += __shfl_xor(s, 4, 64); s += __shfl_xor(s, 8, 64);
        sumAcc[i] = s;
    }
    int qrow0 = qt * 64 + wv * 16 + lg * 4;
#pragma unroll
    for (int r = 0; r < 4; ++r) {
        int qloc = qrow0 + r;
        if (qloc < NNODES) {
            float* pp = Part + ((size_t)(mc * 8192) + b * 2048 + qloc) * 72;
            pp[0 * 16 + l15] = O[0][r];
            pp[1 * 16 + l15] = O[1][r];
            pp[2 * 16 + l15] = O[2][r];
            pp[3 * 16 + l15] = O[3][r];
            if (l15 == 0) {
                pp[64] = sumAcc[0 * 4 + r];
                pp[65] = sumAcc[1 * 4 + r];
                pp[66] = sumAcc[2 * 4 + r];
                pp[67] = sumAcc[3 * 4 + r];
            }
        }
    }
}

// ---- attn1 merge + out-proj ----
__global__ __launch_bounds__(256) void k_a1m(const float* __restrict__ Part,
        const float* __restrict__ ow, const float* __restrict__ ob,
        float* __restrict__ y1) {
    __shared__ float owl[64][64];
    int tid = threadIdx.x;
    for (int i = tid; i < 4096; i += 256) ((float*)owl)[i] = ow[i];
    __syncthreads();
    int t = blockIdx.x * 256 + tid;        // 0..8191
    int b = t >> 11, ql = t & 2047;
    if (ql >= NNODES) return;

    float acc[68];
#pragma unroll
    for (int k = 0; k < 68; ++k) acc[k] = 0.f;
    for (int mc = 0; mc < 8; ++mc) {
        const float* p = Part + ((size_t)(mc * 8192) + b * 2048 + ql) * 72;
#pragma unroll
        for (int k = 0; k < 68; ++k) acc[k] += p[k];
    }
#pragma unroll
    for (int e = 0; e < 64; ++e) acc[e] /= acc[64 + (e >> 4)];
    float* yo = y1 + (size_t)(b * NNODES + ql) * 64;
    for (int d = 0; d < 64; d += 4) {
        float rr[4];
#pragma unroll
        for (int u = 0; u < 4; ++u) {
            float s = ob[d + u];
            const float4* wr = (const float4*)&owl[d + u][0];
#pragma unroll
            for (int e4 = 0; e4 < 16; ++e4) {
                float4 w4 = wr[e4];
                s = fmaf(acc[e4 * 4 + 0], w4.x, s);
                s = fmaf(acc[e4 * 4 + 1], w4.y, s);
                s = fmaf(acc[e4 * 4 + 2], w4.z, s);
                s = fmaf(acc[e4 * 4 + 3], w4.w, s);
            }
            rr[u] = s;
        }
        *(float4*)(yo + d) = make_float4(rr[0], rr[1], rr[2], rr[3]);
    }
}

// ---- attn2 MFMA flash (unchanged round 8) ----
__global__ __launch_bounds__(256, 2) void k_a2(const float* __restrict__ y1,
        const unsigned* __restrict__ maskTg, float* __restrict__ Part) {
    __shared__ unsigned short Yhi[64 * 72];
    __shared__ unsigned short Ylo[64 * 72];
    __shared__ unsigned short Yt[64 * 72];
    __shared__ unsigned short Pl[4 * 16 * 72];
    __shared__ unsigned maskTl[2 * 256];

    int tid = threadIdx.x, bid = blockIdx.x;
    int b = bid >> 8, qt = (bid >> 3) & 31, mc = bid & 7;
    int wv = tid >> 6, l = tid & 63;
    int l15 = l & 15, lg = l >> 4;
    const float* y1b = y1 + (size_t)(b * NNODES) * 64;

    for (int i = tid; i < 512; i += 256) {
        int wq = i >> 8, ml = i & 255;
        int mg = mc * 256 + ml;
        maskTl[wq * 256 + ml] =
            (mg < NNODES) ? maskTg[((size_t)(b * 64) + qt * 2 + wq) * 2048 + mg] : 0u;
    }

    int qloc_f = min(qt * 64 + wv * 16 + l15, NNODES - 1);
    const float* qrow = y1b + (size_t)qloc_f * 64;
    short8 Ahi0, Ahi1, Alo0, Alo1;
#pragma unroll
    for (int j = 0; j < 8; ++j) {
        float x0 = qrow[lg * 8 + j];
        unsigned short h0 = f2bf(x0);
        Ahi0[j] = (short)h0; Alo0[j] = (short)f2bf(x0 - bf2f(h0));
        float x1 = qrow[32 + lg * 8 + j];
        unsigned short h1 = f2bf(x1);
        Ahi1[j] = (short)h1; Alo1[j] = (short)f2bf(x1 - bf2f(h1));
    }

    f32x4 O0 = {0.f,0.f,0.f,0.f}, O1 = {0.f,0.f,0.f,0.f};
    f32x4 O2 = {0.f,0.f,0.f,0.f}, O3 = {0.f,0.f,0.f,0.f};
    float sumAcc[4] = {0.f, 0.f, 0.f, 0.f};
    int wvbase = wv * 16 * 72;
    int bitb = (wv & 1) * 16 + lg * 4;
    int mword = wv >> 1;

    for (int step = 0; step < 4; ++step) {
        int m0 = mc * 256 + step * 64;
        for (int i = tid; i < 1024; i += 256) {
            int r = i >> 4, c4 = i & 15;
            int mg = m0 + r;
            float4 v = make_float4(0.f, 0.f, 0.f, 0.f);
            if (mg < NNODES) v = *(const float4*)(y1b + (size_t)mg * 64 + c4 * 4);
            unsigned short h0 = f2bf(v.x), h1 = f2bf(v.y), h2 = f2bf(v.z), h3 = f2bf(v.w);
            ushort4 hv = {h0, h1, h2, h3};
            *(ushort4*)&Yhi[r * 72 + c4 * 4] = hv;
            ushort4 lv = {f2bf(v.x - bf2f(h0)), f2bf(v.y - bf2f(h1)),
                          f2bf(v.z - bf2f(h2)), f2bf(v.w - bf2f(h3))};
            *(ushort4*)&Ylo[r * 72 + c4 * 4] = lv;
            Yt[(c4 * 4 + 0) * 72 + r] = h0;
            Yt[(c4 * 4 + 1) * 72 + r] = h1;
            Yt[(c4 * 4 + 2) * 72 + r] = h2;
            Yt[(c4 * 4 + 3) * 72 + r] = h3;
        }
        __syncthreads();

#pragma unroll
        for (int mt = 0; mt < 4; ++mt) {
            int mrow = mt * 16 + l15;
            short8 bh0 = *(const short8*)&Yhi[mrow * 72 + lg * 8];
            short8 bh1 = *(const short8*)&Yhi[mrow * 72 + 32 + lg * 8];
            short8 bl0 = *(const short8*)&Ylo[mrow * 72 + lg * 8];
            short8 bl1 = *(const short8*)&Ylo[mrow * 72 + 32 + lg * 8];
            f32x4 S = {0.f, 0.f, 0.f, 0.f};
            S = MFMA16(Ahi0, bh0, S); S = MFMA16(Ahi1, bh1, S);
            S = MFMA16(Alo0, bh0, S); S = MFMA16(Alo1, bh1, S);
            S = MFMA16(Ahi0, bl0, S); S = MFMA16(Ahi1, bl1, S);
            unsigned mwv = maskTl[mword * 256 + step * 64 + mt * 16 + l15];
#pragma unroll
            for (int r = 0; r < 4; ++r) {
                float p = ((mwv >> (bitb + r)) & 1u) ? __expf(S[r] * 0.125f) : 0.f;
                sumAcc[r] += p;
                Pl[wvbase + (lg * 4 + r) * 72 + mt * 16 + l15] = f2bf(p);
            }
        }

#pragma unroll
        for (int ks = 0; ks < 2; ++ks) {
            short8 pf = *(const short8*)&Pl[wvbase + l15 * 72 + ks * 32 + lg * 8];
            short8 v0 = *(const short8*)&Yt[(0 * 16 + l15) * 72 + ks * 32 + lg * 8];
            O0 = MFMA16(pf, v0, O0);
            short8 v1 = *(const short8*)&Yt[(1 * 16 + l15) * 72 + ks * 32 + lg * 8];
            O1 = MFMA16(pf, v1, O1);
            short8 v2 = *(const short8*)&Yt[(2 * 16 + l15) * 72 + ks * 32 + lg * 8];
            O2 = MFMA16(pf, v2, O2);
            short8 v3 = *(const short8*)&Yt[(3 * 16 + l15) * 72 + ks * 32 + lg * 8];
            O3 = MFMA16(pf, v3, O3);
        }
        __syncthreads();
    }

#pragma unroll
    for (int r = 0; r < 4; ++r) {
        float s = sumAcc[r];
        s += __shfl_xor(s, 1, 64); s += __shfl_xor(s, 2, 64);
        s += __shfl_xor(s, 4, 64); s += __shfl_xor(s, 8, 64);
        sumAcc[r] = s;
    }
    int qrow_base = qt * 64 + wv * 16 + lg * 4;
#pragma unroll
    for (int r = 0; r < 4; ++r) {
        int qloc = qrow_base + r;
        if (qloc < NNODES) {
            float* pp = Part + ((size_t)(mc * 8192) + b * 2048 + qloc) * 72;
            pp[0 * 16 + l15] = O0[r];
            pp[1 * 16 + l15] = O1[r];
            pp[2 * 16 + l15] = O2[r];
            pp[3 * 16 + l15] = O3[r];
            if (l15 == 0) pp[64] = sumAcc[r];
        }
    }
}

// ---- attn2 merge ----
__global__ __launch_bounds__(256) void k_a2m(const float* __restrict__ Part,
        const float* __restrict__ node,
        const float* __restrict__ ga, const float* __restrict__ ba,
        const float* __restrict__ pw, const float* __restrict__ pb,
        float* __restrict__ out) {
    __shared__ float pwl[24 * 64];
    __shared__ float gal[64], bal[64], pbl[24];
    int tid = threadIdx.x;
    for (int i = tid; i < 24 * 64; i += 256) pwl[i] = pw[i];
    if (tid < 64) { gal[tid] = ga[tid]; bal[tid] = ba[tid]; }
    if (tid < 24) pbl[tid] = pb[tid];
    __syncthreads();
    int t = blockIdx.x * 256 + tid;
    int b = t >> 11, ql = t & 2047;
    if (ql >= NNODES) return;
    int qg = b * NNODES + ql;

    float acc[65];
#pragma unroll
    for (int k = 0; k < 65; ++k) acc[k] = 0.f;
    for (int mc = 0; mc < 8; ++mc) {
        const float* p = Part + ((size_t)(mc * 8192) + b * 2048 + ql) * 72;
#pragma unroll
        for (int k = 0; k < 65; ++k) acc[k] += p[k];
    }
    float inv = 1.0f / acc[64];
    const float* nd = node + (size_t)qg * 64;
    float oo[64];
    float s1 = 0.f, s2 = 0.f;
#pragma unroll
    for (int d = 0; d < 64; ++d) {
        float v = acc[d] * inv + nd[d];
        oo[d] = v;
        s1 += v; s2 += v * v;
    }
    float mu = s1 * (1.f / 64.f);
    float var = s2 * (1.f / 64.f) - mu * mu;
    float rs = rsqrtf(var + 1e-5f);
#pragma unroll
    for (int d = 0; d < 64; ++d) oo[d] = (oo[d] - mu) * rs * gal[d] + bal[d];

    float* op = out + (size_t)qg * HORZ;
    for (int r = 0; r < HORZ; ++r) {
        float s = pbl[r];
        const float4* wr = (const float4*)&pwl[r * 64];
#pragma unroll
        for (int e4 = 0; e4 < 16; ++e4) {
            float4 w4 = wr[e4];
            s = fmaf(oo[e4 * 4 + 0], w4.x, s);
            s = fmaf(oo[e4 * 4 + 1], w4.y, s);
            s = fmaf(oo[e4 * 4 + 2], w4.z, s);
            s = fmaf(oo[e4 * 4 + 3], w4.w, s);
        }
        op[r] = s;
    }
}

extern "C" void kernel_launch(void* const* d_in, const int* in_sizes, int n_in,
                              void* d_out, int out_size, void* d_ws, size_t ws_size,
                              hipStream_t stream) {
    const float* x      = (const float*)d_in[0];
    const float* conv_w = (const float*)d_in[1];
    const float* conv_b = (const float*)d_in[2];
    const float* bn_g   = (const float*)d_in[3];
    const float* bn_b   = (const float*)d_in[4];
    const float* proj_w = (const float*)d_in[5];
    const float* proj_b = (const float*)d_in[6];
    const float* ln1_g  = (const float*)d_in[7];
    const float* ln1_b  = (const float*)d_in[8];
    const float* src_w  = (const float*)d_in[9];
    const float* src_b  = (const float*)d_in[10];
    const float* dst_w  = (const float*)d_in[11];
    const float* dst_b  = (const float*)d_in[12];
    const float* edge_s = (const float*)d_in[13];
    const float* ipw    = (const float*)d_in[14];
    const float* ipb    = (const float*)d_in[15];
    const float* out_w  = (const float*)d_in[16];
    const float* out_b  = (const float*)d_in[17];
    const float* lnA_g  = (const float*)d_in[18];
    const float* lnA_b  = (const float*)d_in[19];
    const float* pred_w = (const float*)d_in[20];
    const float* pred_b = (const float*)d_in[21];
    float* out = (float*)d_out;

    float* ws = (float*)d_ws;
    float*    projT = ws;                         //   49152
    float*    node  = projT + 49152;              //  512000
    float*    y1    = node + 512000;              //  512000
    float*    Qb    = y1 + 512000;                //  512000
    float*    Kb    = Qb + 512000;                //  512000
    float*    Vb    = Kb + 512000;                //  512000
    float*    Sbuf  = Vb + 512000;                //  256000
    float*    Dbuf  = Sbuf + 256000;              //  256000
    unsigned* maskT = (unsigned*)(Dbuf + 256000); // 524288 u32
    float*    ssqP  = (float*)(maskT + 524288);   //   32000
    float*    adv   = ssqP + 32000;               //    8000
    float*    Part  = adv + 8000;                 // 8704000

    k_tr<<<192, 256, 0, stream>>>(proj_w, projT);
    k_enc<<<1000, 64, 0, stream>>>(x, conv_w, conv_b, bn_g, bn_b,
                                   projT, proj_b, ln1_g, ln1_b, node);
    k_qkv<<<1000, 256, 0, stream>>>(node, ipw, ipb, src_w, src_b, dst_w, dst_b,
                                    Qb, Kb, Vb, Sbuf, Dbuf);
    k_adj<<<512, 256, 0, stream>>>(Sbuf, Dbuf, edge_s, maskT, ssqP, adv);
    k_diag<<<32, 256, 0, stream>>>(ssqP, adv, maskT);
    k_a1<<<1024, 256, 0, stream>>>(Qb, Kb, Vb, Part);
    k_a1m<<<32, 256, 0, stream>>>(Part, out_w, out_b, y1);
    k_a2<<<1024, 256, 0, stream>>>(y1, maskT, Part);
    k_a2m<<<32, 256, 0, stream>>>(Part, node, lnA_g, lnA_b, pred_w, pred_b, out);
}